// Round 6
// baseline (408.465 us; speedup 1.0000x reference)
//
#include <hip/hip_runtime.h>
#include <stdint.h>

#define V_CONST 50257
#define NMASK ((V_CONST + 31) / 32)
#define KTOP 50
#define CAND_CAP 1024
#define NTHREADS 1024
#define THR_SCREEN 13.0f
#define C_TEMP 1.25f
#define C_PEN ((float)(1.25 / 1.2))
#define H0 25132              // half split, multiple of 4 (keeps alignment law)
#define CAP_H 512
#define THREEFRY_PARTITIONABLE 1

__device__ __forceinline__ void tf_round(uint32_t &x0, uint32_t &x1, int r) {
  x0 += x1;
  x1 = (x1 << r) | (x1 >> (32 - r));
  x1 ^= x0;
}

// Threefry-2x32, 20 rounds, key = (0, 42)  [jax.random.key(42)]
__device__ __forceinline__ uint2 threefry_k_0_42(uint32_t x0, uint32_t x1) {
  const uint32_t ks0 = 0u;
  const uint32_t ks1 = 42u;
  const uint32_t ks2 = 0x1BD11BDAu ^ 0u ^ 42u;
  x0 += ks0; x1 += ks1;
  tf_round(x0, x1, 13); tf_round(x0, x1, 15); tf_round(x0, x1, 26); tf_round(x0, x1, 6);
  x0 += ks1; x1 += ks2 + 1u;
  tf_round(x0, x1, 17); tf_round(x0, x1, 29); tf_round(x0, x1, 16); tf_round(x0, x1, 24);
  x0 += ks2; x1 += ks0 + 2u;
  tf_round(x0, x1, 13); tf_round(x0, x1, 15); tf_round(x0, x1, 26); tf_round(x0, x1, 6);
  x0 += ks0; x1 += ks1 + 3u;
  tf_round(x0, x1, 17); tf_round(x0, x1, 29); tf_round(x0, x1, 16); tf_round(x0, x1, 24);
  x0 += ks1; x1 += ks2 + 4u;
  tf_round(x0, x1, 13); tf_round(x0, x1, 15); tf_round(x0, x1, 26); tf_round(x0, x1, 6);
  x0 += ks2; x1 += ks0 + 5u;
  uint2 r; r.x = x0; r.y = x1; return r;
}

__device__ __forceinline__ float gumbel_at(uint32_t p, uint32_t half_total) {
  uint32_t bits;
#if THREEFRY_PARTITIONABLE
  uint2 o = threefry_k_0_42(0u, p);
  bits = o.x ^ o.y;
#else
  if (p < half_total) {
    uint2 o = threefry_k_0_42(p, p + half_total);
    bits = o.x;
  } else {
    uint2 o = threefry_k_0_42(p - half_total, p);
    bits = o.y;
  }
#endif
  uint32_t ub = (bits >> 9) | 0x3F800000u;
  float u = __uint_as_float(ub) - 1.0f;
  u = u + 1.17549435e-38f;
  u = fmaxf(1.17549435e-38f, u);
  return -logf(-logf(u));
}

__device__ __forceinline__ uint32_t f2u_desc(float f) {
  uint32_t b = __float_as_uint(f);
  return (b & 0x80000000u) ? ~b : (b | 0x80000000u);
}
__device__ __forceinline__ float u2f(uint32_t u) {
  uint32_t b = (u & 0x80000000u) ? (u & 0x7FFFFFFFu) : ~u;
  return __uint_as_float(b);
}

// ---------- shared tail: sort/certify done by caller; this does topk..scatter
__device__ void sample_tail(int n, uint32_t* su, int* sidx, float* eg, float* gg,
                            float* out, float* prow, int b, int tid,
                            int* s_nsurv, int* s_rlast, float* s_z2) {
  if (tid == 0) {
    int kpos = (n < KTOP) ? (n - 1) : (KTOP - 1);
    uint32_t kth = su[kpos];
    int ns = kpos + 1;
    while (ns < n && su[ns] == kth) ns++;
    *s_nsurv = ns;
  }
  __syncthreads();
  const int nsurv = *s_nsurv;
  const float s0 = u2f(su[0]);
  const uint32_t half_total = (uint32_t)((size_t)256 * V_CONST / 2);

  for (int r = tid; r < nsurv; r += NTHREADS) {
    float f = u2f(su[r]);
    eg[r] = expf(f - s0);
    gg[r] = gumbel_at((uint32_t)(b * V_CONST + sidx[r]), half_total);
  }
  __syncthreads();

  if (tid == 0) {
    float zall = 0.f;
    for (int r = 0; r < nsurv; r++) zall += eg[r];
    float cum = 0.f;
    int rlast = 0;
    for (int r = 0; r < nsurv; r++) {
      cum += eg[r] / zall;
      if (r == 0 || cum <= 0.9f) rlast = r;
      else break;
    }
    float z2 = 0.f;
    for (int r = 0; r <= rlast; r++) z2 += eg[r];
    float best = -3.402823466e38f; int besti = V_CONST;
    for (int r = 0; r <= rlast; r++) {
      float sc = u2f(su[r]) + gg[r];
      int idx = sidx[r];
      if (sc > best || (sc == best && idx < besti)) { best = sc; besti = idx; }
    }
    out[b] = (float)besti;
    *s_rlast = rlast; *s_z2 = z2;
  }
  __syncthreads();
  const int rlast = *s_rlast;
  const float z2 = *s_z2;
  for (int r = tid; r <= rlast; r += NTHREADS) {
    prow[sidx[r]] = eg[r] / z2;
  }
}

// ============ fused kernel: 2 blocks per row, last finisher samples ==========
__global__ __launch_bounds__(NTHREADS) void fused_kernel(
    const float* __restrict__ logits, const int* __restrict__ generated,
    float* __restrict__ out, int* __restrict__ tickets, int* __restrict__ counts,
    uint2* __restrict__ pairs, int B, int T) {
  const int bid = blockIdx.x;
  const int b = bid >> 1, h = bid & 1;
  const int tid = threadIdx.x;
  const int vlo = h ? H0 : 0;
  const int len = h ? (V_CONST - H0) : H0;
  const int vhi = vlo + len;
  const int w0 = vlo >> 5;
  const int nw = ((vhi + 31) >> 5) - w0;

  __shared__ uint32_t mask[NMASK];   // half-mask during screen; full in fallback
  __shared__ uint32_t cu[CAND_CAP];
  __shared__ int      cidx[CAND_CAP];
  __shared__ uint32_t su[CAND_CAP];
  __shared__ int      sidx[CAND_CAP];
  __shared__ float    eg[CAND_CAP];
  __shared__ float    gg[CAND_CAP];
  __shared__ int s_cnt, s_winner, s_nsurv, s_rlast;
  __shared__ float s_z2;

  // ---- half present-mask ----
  for (int i = tid; i < nw; i += NTHREADS) mask[i] = 0u;
  if (tid == 0) s_cnt = 0;
  __syncthreads();
  const int* grow = generated + (size_t)b * T;
  for (int i = tid; i < T; i += NTHREADS) {
    int tok = grow[i];
    if (tok >= vlo && tok < vhi)
      atomicOr(&mask[(tok >> 5) - w0], 1u << (tok & 31));
  }
  __syncthreads();

  // ---- read-only screen of this half; exact-key pairs straight to ws ----
  const float* lrow = logits + (size_t)b * V_CONST;
  float* prow = out + B + (size_t)b * V_CONST;
  const int aoff = (4 - (b & 3)) & 3;        // (b*V+vlo) mod 4 == b mod 4
  const int body4 = (len - aoff) >> 2;
  const int tailn = (len - aoff) & 3;
  const float4* arow4 = (const float4*)(lrow + vlo + aoff);
  uint2* mypairs = pairs + (size_t)bid * CAP_H;

#define SCREEN1(xv, vv) do {                                          \
    int v_ = (vv); float x_ = (xv);                                   \
    uint32_t pres_ = (mask[(v_ >> 5) - w0] >> (v_ & 31)) & 1u;        \
    float m_ = pres_ ? C_PEN : C_TEMP;                                \
    if (x_ * m_ >= THR_SCREEN) {                                      \
      float xe_ = x_ / 0.8f; if (pres_) xe_ = xe_ / 1.2f;             \
      int p_ = atomicAdd(&s_cnt, 1);                                  \
      if (p_ < CAP_H) mypairs[p_] = make_uint2(f2u_desc(xe_), (uint32_t)v_); \
    } } while (0)

  for (int t = tid; t < body4; t += NTHREADS) {
    float4 r = arow4[t];
    int v0 = vlo + aoff + (t << 2);
    SCREEN1(r.x, v0 + 0);
    SCREEN1(r.y, v0 + 1);
    SCREEN1(r.z, v0 + 2);
    SCREEN1(r.w, v0 + 3);
  }
  if (tid < aoff + tailn) {
    int v = (tid < aoff) ? (vlo + tid) : (vhi - tailn + (tid - aoff));
    SCREEN1(lrow[v], v);
  }
#undef SCREEN1
  __syncthreads();
  if (tid == 0) counts[bid] = s_cnt;

  // ---- zero-fill my probs half (same alignment as logits half) ----
  {
    float4* orow4 = (float4*)(prow + vlo + aoff);
    const float4 z4 = make_float4(0.f, 0.f, 0.f, 0.f);
    for (int t = tid; t < body4; t += NTHREADS) orow4[t] = z4;
    if (tid < aoff + tailn) {
      int v = (tid < aoff) ? (vlo + tid) : (vhi - tailn + (tid - aoff));
      prow[v] = 0.f;
    }
  }

  // ---- publish, take ticket; second finisher samples this row ----
  __threadfence();
  if (tid == 0) s_winner = (atomicAdd(&tickets[b], 1) == 1) ? 1 : 0;
  __syncthreads();
  if (!s_winner) return;
  __threadfence();   // acquire side

  int c0 = counts[2 * b], c1 = counts[2 * b + 1];
  int total = c0 + c1;
  int n = 0;
  bool ok = false;

  if (c0 <= CAP_H && c1 <= CAP_H && total >= KTOP && total <= CAND_CAP) {
    const uint2* pp0 = pairs + (size_t)(2 * b) * CAP_H;
    const uint2* pp1 = pairs + (size_t)(2 * b + 1) * CAP_H;
    for (int i = tid; i < c0; i += NTHREADS) {
      uint2 pr = pp0[i]; cu[i] = pr.x; cidx[i] = (int)pr.y;
    }
    for (int i = tid; i < c1; i += NTHREADS) {
      uint2 pr = pp1[i]; cu[c0 + i] = pr.x; cidx[c0 + i] = (int)pr.y;
    }
    n = total;
    __syncthreads();
    for (int i = tid; i < n; i += NTHREADS) {
      uint32_t ui = cu[i]; int ii = cidx[i];
      int rank = 0;
      for (int j = 0; j < n; j++) {
        uint32_t uj = cu[j];
        rank += ((uj > ui) || (uj == ui && cidx[j] < ii)) ? 1 : 0;
      }
      su[rank] = ui; sidx[rank] = ii;
    }
    __syncthreads();
    ok = (su[KTOP - 1] >= f2u_desc(THR_SCREEN) + 64u);
  }

  if (!ok) {
    // ---- fallback: full-row bisection re-scan (never taken on this data) ----
    for (int i = tid; i < NMASK; i += NTHREADS) mask[i] = 0u;
    __syncthreads();
    for (int i = tid; i < T; i += NTHREADS) {
      int tok = grow[i];
      atomicOr(&mask[tok >> 5], 1u << (tok & 31));
    }
    __syncthreads();
    const int ftailn = (V_CONST - aoff) & 3;
    const int fbody4 = (V_CONST - aoff) >> 2;
    const float4* frow4 = (const float4*)(lrow + aoff);
    float thr = THR_SCREEN;
    uint32_t ulo_ = 0u, uhi_ = 0xFFFFFFFFu;
    n = 0;
    for (int attempt = 0; attempt < 64; ++attempt) {
      __syncthreads();
      if (tid == 0) s_cnt = 0;
      __syncthreads();
      for (int t = tid; t < fbody4; t += NTHREADS) {
        float4 r = frow4[t];
        int v0 = aoff + (t << 2);
        uint32_t w = (mask[v0 >> 5] >> (v0 & 31)) & 0xFu;
        float m0 = (w & 1u) ? C_PEN : C_TEMP;
        float m1 = (w & 2u) ? C_PEN : C_TEMP;
        float m2 = (w & 4u) ? C_PEN : C_TEMP;
        float m3 = (w & 8u) ? C_PEN : C_TEMP;
        if (r.x * m0 >= thr) { int p = atomicAdd(&s_cnt, 1); if (p < CAND_CAP) { cu[p] = __float_as_uint(r.x); cidx[p] = v0; } }
        if (r.y * m1 >= thr) { int p = atomicAdd(&s_cnt, 1); if (p < CAND_CAP) { cu[p] = __float_as_uint(r.y); cidx[p] = v0 + 1; } }
        if (r.z * m2 >= thr) { int p = atomicAdd(&s_cnt, 1); if (p < CAND_CAP) { cu[p] = __float_as_uint(r.z); cidx[p] = v0 + 2; } }
        if (r.w * m3 >= thr) { int p = atomicAdd(&s_cnt, 1); if (p < CAND_CAP) { cu[p] = __float_as_uint(r.w); cidx[p] = v0 + 3; } }
      }
      if (tid < aoff + ftailn) {
        int v = (tid < aoff) ? tid : (V_CONST - ftailn) + (tid - aoff);
        float x = lrow[v];
        float m = ((mask[v >> 5] >> (v & 31)) & 1u) ? C_PEN : C_TEMP;
        if (x * m >= thr) { int p = atomicAdd(&s_cnt, 1); if (p < CAND_CAP) { cu[p] = __float_as_uint(x); cidx[p] = v; } }
      }
      __syncthreads();
      const int tot = s_cnt;
      n = (tot < CAND_CAP) ? tot : CAND_CAP;
      const bool window = (tot >= KTOP && tot <= CAND_CAP);
      const bool last = (attempt == 63);
      if (window || last) {
        if (n > 0) {
          for (int i = tid; i < n; i += NTHREADS) {
            float x = __uint_as_float(cu[i]);
            int v = cidx[i];
            float xe = x / 0.8f;
            if ((mask[v >> 5] >> (v & 31)) & 1u) xe = xe / 1.2f;
            cu[i] = f2u_desc(xe);
          }
          __syncthreads();
          for (int i = tid; i < n; i += NTHREADS) {
            uint32_t ui = cu[i]; int ii = cidx[i];
            int rank = 0;
            for (int j = 0; j < n; j++) {
              uint32_t uj = cu[j];
              rank += ((uj > ui) || (uj == ui && cidx[j] < ii)) ? 1 : 0;
            }
            su[rank] = ui; sidx[rank] = ii;
          }
          __syncthreads();
        }
        if (window) {
          if (su[KTOP - 1] >= f2u_desc(thr) + 64u) break;
          if (last) break;
          thr = u2f(su[KTOP - 1] >= 96u ? su[KTOP - 1] - 96u : 0u);
        } else break;
      } else if (tot < KTOP) {
        uhi_ = f2u_desc(thr);
        if (attempt == 0) thr = 11.0f;
        else {
          uint32_t mid = ulo_ + (uhi_ - ulo_) / 2u;
          if (mid >= uhi_) mid = uhi_ - 1u;
          thr = u2f(mid);
        }
      } else {
        ulo_ = f2u_desc(thr);
        uint32_t mid = ulo_ + (uhi_ - ulo_) / 2u;
        if (mid <= ulo_) mid = ulo_ + 1u;
        thr = u2f(mid);
      }
    }
  }

  if (n == 0) { if (tid == 0) out[b] = 0.f; return; }
  sample_tail(n, su, sidx, eg, gg, out, prow, b, tid, &s_nsurv, &s_rlast, &s_z2);
}

// ============ mono kernel (R5, known-good) — used if ws too small ============
__global__ __launch_bounds__(NTHREADS) void mono_kernel(
    const float* __restrict__ logits, const int* __restrict__ generated,
    float* __restrict__ out, int B, int T) {
  const int b = blockIdx.x;
  const int tid = threadIdx.x;
  __shared__ uint32_t mask[NMASK];
  __shared__ uint32_t cu[CAND_CAP];
  __shared__ int      cidx[CAND_CAP];
  __shared__ uint32_t su[CAND_CAP];
  __shared__ int      sidx[CAND_CAP];
  __shared__ float    eg[CAND_CAP];
  __shared__ float    gg[CAND_CAP];
  __shared__ int s_ncand, s_nsurv, s_rlast;
  __shared__ float s_z2;

  for (int i = tid; i < NMASK; i += NTHREADS) mask[i] = 0u;
  if (tid == 0) s_ncand = 0;
  __syncthreads();
  const int* grow = generated + (size_t)b * T;
  for (int i = tid; i < T; i += NTHREADS) {
    int tok = grow[i];
    atomicOr(&mask[tok >> 5], 1u << (tok & 31));
  }
  __syncthreads();

  const float* lrow = logits + (size_t)b * V_CONST;
  float* prow = out + B + (size_t)b * V_CONST;
  const int aoff = (4 - (b & 3)) & 3;
  const int tailn = (V_CONST - aoff) & 3;
  const int body4 = (V_CONST - aoff) >> 2;
  const float4* arow4 = (const float4*)(lrow + aoff);
  float4* orow4 = (float4*)(prow + aoff);
  const float4 z4 = make_float4(0.f, 0.f, 0.f, 0.f);

#define SCREEN1(xv, vv) do {                                          \
    int v_ = (vv); float x_ = (xv);                                   \
    uint32_t pres_ = (mask[v_ >> 5] >> (v_ & 31)) & 1u;               \
    float m_ = pres_ ? C_PEN : C_TEMP;                                \
    if (x_ * m_ >= THR_SCREEN) {                                      \
      float xe_ = x_ / 0.8f; if (pres_) xe_ = xe_ / 1.2f;             \
      int p_ = atomicAdd(&s_ncand, 1);                                \
      if (p_ < CAND_CAP) { cu[p_] = f2u_desc(xe_); cidx[p_] = v_; }   \
    } } while (0)
  for (int t = tid; t < body4; t += NTHREADS) {
    float4 r = arow4[t];
    orow4[t] = z4;
    int v0 = aoff + (t << 2);
    SCREEN1(r.x, v0 + 0);
    SCREEN1(r.y, v0 + 1);
    SCREEN1(r.z, v0 + 2);
    SCREEN1(r.w, v0 + 3);
  }
  if (tid < aoff + tailn) {
    int v = (tid < aoff) ? tid : (V_CONST - tailn) + (tid - aoff);
    prow[v] = 0.f;
    SCREEN1(lrow[v], v);
  }
#undef SCREEN1
  __syncthreads();

  const int total = s_ncand;
  int n = (total < CAND_CAP) ? total : CAND_CAP;
  bool ok = false;
  if (total >= KTOP && total <= CAND_CAP) {
    for (int i = tid; i < n; i += NTHREADS) {
      uint32_t ui = cu[i]; int ii = cidx[i];
      int rank = 0;
      for (int j = 0; j < n; j++) {
        uint32_t uj = cu[j];
        rank += ((uj > ui) || (uj == ui && cidx[j] < ii)) ? 1 : 0;
      }
      su[rank] = ui; sidx[rank] = ii;
    }
    __syncthreads();
    ok = (su[KTOP - 1] >= f2u_desc(THR_SCREEN) + 64u);
  } else {
    __syncthreads();
  }
  if (!ok) {
    float thr = THR_SCREEN;
    uint32_t ulo_ = 0u, uhi_ = 0xFFFFFFFFu;
    n = 0;
    for (int attempt = 0; attempt < 64; ++attempt) {
      __syncthreads();
      if (tid == 0) s_ncand = 0;
      __syncthreads();
      for (int t = tid; t < body4; t += NTHREADS) {
        float4 r = arow4[t];
        int v0 = aoff + (t << 2);
        uint32_t w = (mask[v0 >> 5] >> (v0 & 31)) & 0xFu;
        float m0 = (w & 1u) ? C_PEN : C_TEMP;
        float m1 = (w & 2u) ? C_PEN : C_TEMP;
        float m2 = (w & 4u) ? C_PEN : C_TEMP;
        float m3 = (w & 8u) ? C_PEN : C_TEMP;
        if (r.x * m0 >= thr) { int p = atomicAdd(&s_ncand, 1); if (p < CAND_CAP) { cu[p] = __float_as_uint(r.x); cidx[p] = v0; } }
        if (r.y * m1 >= thr) { int p = atomicAdd(&s_ncand, 1); if (p < CAND_CAP) { cu[p] = __float_as_uint(r.y); cidx[p] = v0 + 1; } }
        if (r.z * m2 >= thr) { int p = atomicAdd(&s_ncand, 1); if (p < CAND_CAP) { cu[p] = __float_as_uint(r.z); cidx[p] = v0 + 2; } }
        if (r.w * m3 >= thr) { int p = atomicAdd(&s_ncand, 1); if (p < CAND_CAP) { cu[p] = __float_as_uint(r.w); cidx[p] = v0 + 3; } }
      }
      if (tid < aoff + tailn) {
        int v = (tid < aoff) ? tid : (V_CONST - tailn) + (tid - aoff);
        float x = lrow[v];
        float m = ((mask[v >> 5] >> (v & 31)) & 1u) ? C_PEN : C_TEMP;
        if (x * m >= thr) { int p = atomicAdd(&s_ncand, 1); if (p < CAND_CAP) { cu[p] = __float_as_uint(x); cidx[p] = v; } }
      }
      __syncthreads();
      const int tot = s_ncand;
      n = (tot < CAND_CAP) ? tot : CAND_CAP;
      const bool window = (tot >= KTOP && tot <= CAND_CAP);
      const bool last = (attempt == 63);
      if (window || last) {
        if (n > 0) {
          for (int i = tid; i < n; i += NTHREADS) {
            float x = __uint_as_float(cu[i]);
            int v = cidx[i];
            float xe = x / 0.8f;
            if ((mask[v >> 5] >> (v & 31)) & 1u) xe = xe / 1.2f;
            cu[i] = f2u_desc(xe);
          }
          __syncthreads();
          for (int i = tid; i < n; i += NTHREADS) {
            uint32_t ui = cu[i]; int ii = cidx[i];
            int rank = 0;
            for (int j = 0; j < n; j++) {
              uint32_t uj = cu[j];
              rank += ((uj > ui) || (uj == ui && cidx[j] < ii)) ? 1 : 0;
            }
            su[rank] = ui; sidx[rank] = ii;
          }
          __syncthreads();
        }
        if (window) {
          if (su[KTOP - 1] >= f2u_desc(thr) + 64u) break;
          if (last) break;
          thr = u2f(su[KTOP - 1] >= 96u ? su[KTOP - 1] - 96u : 0u);
        } else break;
      } else if (tot < KTOP) {
        uhi_ = f2u_desc(thr);
        if (attempt == 0) thr = 11.0f;
        else {
          uint32_t mid = ulo_ + (uhi_ - ulo_) / 2u;
          if (mid >= uhi_) mid = uhi_ - 1u;
          thr = u2f(mid);
        }
      } else {
        ulo_ = f2u_desc(thr);
        uint32_t mid = ulo_ + (uhi_ - ulo_) / 2u;
        if (mid <= ulo_) mid = ulo_ + 1u;
        thr = u2f(mid);
      }
    }
  }
  if (n == 0) { if (tid == 0) out[b] = 0.f; return; }
  sample_tail(n, su, sidx, eg, gg, out, prow, b, tid, &s_nsurv, &s_rlast, &s_z2);
}

extern "C" void kernel_launch(void* const* d_in, const int* in_sizes, int n_in,
                              void* d_out, int out_size, void* d_ws, size_t ws_size,
                              hipStream_t stream) {
  const float* logits = (const float*)d_in[0];
  const int* generated = (const int*)d_in[1];
  float* out = (float*)d_out;
  const int B = in_sizes[0] / V_CONST;
  const int T = in_sizes[1] / B;

  const size_t pairs_off = 4096;
  const size_t needed = pairs_off + (size_t)2 * B * CAP_H * sizeof(uint2);
  if (ws_size >= needed && B <= 768) {
    int* tickets = (int*)d_ws;                       // [B]
    int* counts = (int*)((char*)d_ws + 2048);        // [2B]
    uint2* pairs = (uint2*)((char*)d_ws + pairs_off);
    hipMemsetAsync(d_ws, 0, 4096, stream);           // reset tickets+counts
    hipLaunchKernelGGL(fused_kernel, dim3(2 * B), dim3(NTHREADS), 0, stream,
                       logits, generated, out, tickets, counts, pairs, B, T);
  } else {
    hipLaunchKernelGGL(mono_kernel, dim3(B), dim3(NTHREADS), 0, stream,
                       logits, generated, out, B, T);
  }
}

// Round 7
// 34.156 us; speedup vs baseline: 11.9588x; 11.9588x over previous
//
#include <hip/hip_runtime.h>
#include <stdint.h>

#define V_CONST 50257
#define NMASK ((V_CONST + 31) / 32)
#define KTOP 50
#define CAND_CAP 1024
#define NTHREADS 1024
#define THR_SCREEN 13.0f
#define C_TEMP 1.25f
#define C_PEN ((float)(1.25 / 1.2))
#define THREEFRY_PARTITIONABLE 1

__device__ __forceinline__ void tf_round(uint32_t &x0, uint32_t &x1, int r) {
  x0 += x1;
  x1 = (x1 << r) | (x1 >> (32 - r));
  x1 ^= x0;
}

// Threefry-2x32, 20 rounds, key = (0, 42)  [jax.random.key(42)]
__device__ __forceinline__ uint2 threefry_k_0_42(uint32_t x0, uint32_t x1) {
  const uint32_t ks0 = 0u;
  const uint32_t ks1 = 42u;
  const uint32_t ks2 = 0x1BD11BDAu ^ 0u ^ 42u;
  x0 += ks0; x1 += ks1;
  tf_round(x0, x1, 13); tf_round(x0, x1, 15); tf_round(x0, x1, 26); tf_round(x0, x1, 6);
  x0 += ks1; x1 += ks2 + 1u;
  tf_round(x0, x1, 17); tf_round(x0, x1, 29); tf_round(x0, x1, 16); tf_round(x0, x1, 24);
  x0 += ks2; x1 += ks0 + 2u;
  tf_round(x0, x1, 13); tf_round(x0, x1, 15); tf_round(x0, x1, 26); tf_round(x0, x1, 6);
  x0 += ks0; x1 += ks1 + 3u;
  tf_round(x0, x1, 17); tf_round(x0, x1, 29); tf_round(x0, x1, 16); tf_round(x0, x1, 24);
  x0 += ks1; x1 += ks2 + 4u;
  tf_round(x0, x1, 13); tf_round(x0, x1, 15); tf_round(x0, x1, 26); tf_round(x0, x1, 6);
  x0 += ks2; x1 += ks0 + 5u;
  uint2 r; r.x = x0; r.y = x1; return r;
}

__device__ __forceinline__ float gumbel_at(uint32_t p, uint32_t half_total) {
  uint32_t bits;
#if THREEFRY_PARTITIONABLE
  uint2 o = threefry_k_0_42(0u, p);
  bits = o.x ^ o.y;
#else
  if (p < half_total) {
    uint2 o = threefry_k_0_42(p, p + half_total);
    bits = o.x;
  } else {
    uint2 o = threefry_k_0_42(p - half_total, p);
    bits = o.y;
  }
#endif
  uint32_t ub = (bits >> 9) | 0x3F800000u;
  float u = __uint_as_float(ub) - 1.0f;
  u = u + 1.17549435e-38f;
  u = fmaxf(1.17549435e-38f, u);
  return -logf(-logf(u));
}

__device__ __forceinline__ uint32_t f2u_desc(float f) {
  uint32_t b = __float_as_uint(f);
  return (b & 0x80000000u) ? ~b : (b | 0x80000000u);
}
__device__ __forceinline__ float u2f(uint32_t u) {
  uint32_t b = (u & 0x80000000u) ? (u & 0x7FFFFFFFu) : ~u;
  return __uint_as_float(b);
}

__global__ __launch_bounds__(NTHREADS) void sample_kernel(
    const float* __restrict__ logits, const int* __restrict__ generated,
    float* __restrict__ out, int B, int T) {
  const int b = blockIdx.x;
  const int tid = threadIdx.x;

  __shared__ uint32_t mask[NMASK];
  __shared__ uint32_t cu[CAND_CAP];
  __shared__ int      cidx[CAND_CAP];
  __shared__ uint32_t su[CAND_CAP];
  __shared__ int      sidx[CAND_CAP];
  __shared__ float    eg[CAND_CAP];   // fallback tail only
  __shared__ float    gg[CAND_CAP];   // fallback tail only
  __shared__ int s_cnt, s_nsurv, s_ovf, s_rlast;
  __shared__ float s_z2;

  // ---- prologue: zero mask + counter (LDS-only barrier, cheap) ----
  for (int i = tid; i < NMASK; i += NTHREADS) mask[i] = 0u;
  if (tid == 0) s_cnt = 0;
  __syncthreads();

  // ---- prefetch generated tokens into registers (consumed after screen) ----
  const int* grow = generated + (size_t)b * T;
  int toks[4];
  int ntok = 0;
  for (int i = tid; i < T && ntok < 4; i += NTHREADS) toks[ntok++] = grow[i];

  // ---- mask-free screen (superset: penalty only lowers keys) + zero-fill ----
  const float* lrow = logits + (size_t)b * V_CONST;
  float* prow = out + B + (size_t)b * V_CONST;
  const int aoff = (4 - (b & 3)) & 3;
  const int tailn = (V_CONST - aoff) & 3;
  const int body4 = (V_CONST - aoff) >> 2;
  const float4* arow4 = (const float4*)(lrow + aoff);
  float4* orow4 = (float4*)(prow + aoff);
  const float4 z4 = make_float4(0.f, 0.f, 0.f, 0.f);

#define PUSH_RAW(xv, vv) do {                                          \
    int p_ = atomicAdd(&s_cnt, 1);                                     \
    if (p_ < CAND_CAP) { cu[p_] = __float_as_uint(xv); cidx[p_] = (vv); } \
  } while (0)

  {
    int t = tid;
    bool has = (t < body4);
    float4 rc;
    if (has) rc = arow4[t];
    while (has) {
      int t2 = t + NTHREADS;
      bool has2 = (t2 < body4);
      float4 rn;
      if (has2) rn = arow4[t2];         // next load in flight over processing
      orow4[t] = z4;
      int v0 = aoff + (t << 2);
      if (rc.x * C_TEMP >= THR_SCREEN) PUSH_RAW(rc.x, v0 + 0);
      if (rc.y * C_TEMP >= THR_SCREEN) PUSH_RAW(rc.y, v0 + 1);
      if (rc.z * C_TEMP >= THR_SCREEN) PUSH_RAW(rc.z, v0 + 2);
      if (rc.w * C_TEMP >= THR_SCREEN) PUSH_RAW(rc.w, v0 + 3);
      t = t2; rc = rn; has = has2;
    }
    if (tid < aoff + tailn) {
      int v = (tid < aoff) ? tid : (V_CONST - tailn) + (tid - aoff);
      prow[v] = 0.f;
      float x = lrow[v];
      if (x * C_TEMP >= THR_SCREEN) PUSH_RAW(x, v);
    }
  }
#undef PUSH_RAW

  // ---- build present mask from prefetched registers ----
  for (int k = 0; k < ntok; k++) {
    int tok = toks[k];
    atomicOr(&mask[tok >> 5], 1u << (tok & 31));
  }
  for (int i = tid + 4 * NTHREADS; i < T; i += NTHREADS) {   // T > 4*NT leftovers
    int tok = grow[i];
    atomicOr(&mask[tok >> 5], 1u << (tok & 31));
  }
  __syncthreads();

  const int total = s_cnt;
  int n = (total < CAND_CAP) ? total : CAND_CAP;
  bool ok = false;

  if (total >= KTOP && total <= CAND_CAP) {
    // exact keys (true IEEE divisions) for candidates only
    for (int i = tid; i < n; i += NTHREADS) {
      float x = __uint_as_float(cu[i]);
      int v = cidx[i];
      float xe = x / 0.8f;
      if ((mask[v >> 5] >> (v & 31)) & 1u) xe = xe / 1.2f;
      cu[i] = f2u_desc(xe);
    }
    __syncthreads();
    // stable rank sort (descending, ties by smaller index)
    for (int i = tid; i < n; i += NTHREADS) {
      uint32_t ui = cu[i]; int ii = cidx[i];
      int rank = 0;
      for (int j = 0; j < n; j++) {
        uint32_t uj = cu[j];
        rank += ((uj > ui) || (uj == ui && cidx[j] < ii)) ? 1 : 0;
      }
      su[rank] = ui; sidx[rank] = ii;
    }
    __syncthreads();
    // certificate: any non-candidate has exact key < f2u(THR)+~4 ulp
    ok = (su[KTOP - 1] >= f2u_desc(THR_SCREEN) + 64u);
  }

  if (!ok) {
    // ---- robust fallback: mask-aware bisection re-scan (never taken here) ----
    float thr = THR_SCREEN;
    uint32_t ulo_ = 0u, uhi_ = 0xFFFFFFFFu;
    n = 0;
    for (int attempt = 0; attempt < 64; ++attempt) {
      __syncthreads();
      if (tid == 0) s_cnt = 0;
      __syncthreads();
      for (int t = tid; t < body4; t += NTHREADS) {
        float4 r = arow4[t];
        int v0 = aoff + (t << 2);
        uint32_t w = (mask[v0 >> 5] >> (v0 & 31)) & 0xFu;
        float m0 = (w & 1u) ? C_PEN : C_TEMP;
        float m1 = (w & 2u) ? C_PEN : C_TEMP;
        float m2 = (w & 4u) ? C_PEN : C_TEMP;
        float m3 = (w & 8u) ? C_PEN : C_TEMP;
        if (r.x * m0 >= thr) { int p = atomicAdd(&s_cnt, 1); if (p < CAND_CAP) { cu[p] = __float_as_uint(r.x); cidx[p] = v0; } }
        if (r.y * m1 >= thr) { int p = atomicAdd(&s_cnt, 1); if (p < CAND_CAP) { cu[p] = __float_as_uint(r.y); cidx[p] = v0 + 1; } }
        if (r.z * m2 >= thr) { int p = atomicAdd(&s_cnt, 1); if (p < CAND_CAP) { cu[p] = __float_as_uint(r.z); cidx[p] = v0 + 2; } }
        if (r.w * m3 >= thr) { int p = atomicAdd(&s_cnt, 1); if (p < CAND_CAP) { cu[p] = __float_as_uint(r.w); cidx[p] = v0 + 3; } }
      }
      if (tid < aoff + tailn) {
        int v = (tid < aoff) ? tid : (V_CONST - tailn) + (tid - aoff);
        float x = lrow[v];
        float m = ((mask[v >> 5] >> (v & 31)) & 1u) ? C_PEN : C_TEMP;
        if (x * m >= thr) { int p = atomicAdd(&s_cnt, 1); if (p < CAND_CAP) { cu[p] = __float_as_uint(x); cidx[p] = v; } }
      }
      __syncthreads();
      const int tot = s_cnt;
      n = (tot < CAND_CAP) ? tot : CAND_CAP;
      const bool window = (tot >= KTOP && tot <= CAND_CAP);
      const bool last = (attempt == 63);
      if (window || last) {
        if (n > 0) {
          for (int i = tid; i < n; i += NTHREADS) {
            float x = __uint_as_float(cu[i]);
            int v = cidx[i];
            float xe = x / 0.8f;
            if ((mask[v >> 5] >> (v & 31)) & 1u) xe = xe / 1.2f;
            cu[i] = f2u_desc(xe);
          }
          __syncthreads();
          for (int i = tid; i < n; i += NTHREADS) {
            uint32_t ui = cu[i]; int ii = cidx[i];
            int rank = 0;
            for (int j = 0; j < n; j++) {
              uint32_t uj = cu[j];
              rank += ((uj > ui) || (uj == ui && cidx[j] < ii)) ? 1 : 0;
            }
            su[rank] = ui; sidx[rank] = ii;
          }
          __syncthreads();
        }
        if (window) {
          if (su[KTOP - 1] >= f2u_desc(thr) + 64u) break;
          if (last) break;
          thr = u2f(su[KTOP - 1] >= 96u ? su[KTOP - 1] - 96u : 0u);
        } else break;
      } else if (tot < KTOP) {
        uhi_ = f2u_desc(thr);
        if (attempt == 0) thr = 11.0f;
        else {
          uint32_t mid = ulo_ + (uhi_ - ulo_) / 2u;
          if (mid >= uhi_) mid = uhi_ - 1u;
          thr = u2f(mid);
        }
      } else {
        ulo_ = f2u_desc(thr);
        uint32_t mid = ulo_ + (uhi_ - ulo_) / 2u;
        if (mid <= ulo_) mid = ulo_ + 1u;
        thr = u2f(mid);
      }
    }
  }

  if (n == 0) { if (tid == 0) out[b] = 0.f; return; }

  // ---- nsurv via wave 0 (ballot), overflow -> serial fallback tail ----
  if (tid < 64) {
    int n64 = (n < 64) ? n : 64;
    uint32_t sur = (tid < n64) ? su[tid] : 0u;
    int kpos = (n < KTOP) ? (n - 1) : (KTOP - 1);
    uint32_t kth = __shfl(sur, kpos, 64);
    unsigned long long m = __ballot(tid < n64 && sur == kth);
    int hi = 63 - __clzll(m);
    if (tid == 0) {
      s_nsurv = hi + 1;
      s_ovf = (hi == n64 - 1 && n > n64) ? 1 : 0;
    }
  }
  __syncthreads();

  const uint32_t half_total = (uint32_t)((size_t)256 * V_CONST / 2);

  if (!s_ovf) {
    // ======== fast tail: everything in wave-0 registers, same op order ======
    if (tid < 64) {
      const int nsurv = s_nsurv;
      uint32_t sur = (tid < nsurv) ? su[tid] : 0u;
      int sidr = (tid < nsurv) ? sidx[tid] : 0x7FFFFFFF;
      float f = u2f(sur);
      float s0 = __shfl(f, 0, 64);
      float egr = 0.f, ggr = 0.f;
      if (tid < nsurv) {
        egr = expf(f - s0);
        ggr = gumbel_at((uint32_t)(b * V_CONST + sidr), half_total);
      }
      float scr = f + ggr;
      // zall: sequential adds, same order as reference loop
      float zall = 0.f;
      for (int j = 0; j < nsurv; j++) zall += __shfl(egr, j, 64);
      // fused cum / z2 / argmax over kept prefix (identical op sequence)
      float cum = 0.f, z2 = 0.f;
      int rlast = 0;
      float best = -3.402823466e38f; int besti = V_CONST;
      for (int j = 0; j < nsurv; j++) {
        float e = __shfl(egr, j, 64);
        cum += e / zall;
        if (j == 0 || cum <= 0.9f) {
          rlast = j;
          z2 += e;
          float sc = __shfl(scr, j, 64);
          int idx = __shfl(sidr, j, 64);
          if (sc > best || (sc == best && idx < besti)) { best = sc; besti = idx; }
        } else break;
      }
      if (tid == 0) out[b] = (float)besti;
      if (tid <= rlast) prow[sidr] = egr / z2;   // scatter straight from lanes
    }
    return;
  }

  // ======== fallback tail (nsurv > 64; never taken on this data) ===========
  {
    const int nsurv = s_nsurv;
    const float s0 = u2f(su[0]);
    for (int r = tid; r < nsurv; r += NTHREADS) {
      float f = u2f(su[r]);
      eg[r] = expf(f - s0);
      gg[r] = gumbel_at((uint32_t)(b * V_CONST + sidx[r]), half_total);
    }
    __syncthreads();
    if (tid == 0) {
      float zall = 0.f;
      for (int r = 0; r < nsurv; r++) zall += eg[r];
      float cum = 0.f;
      int rlast = 0;
      for (int r = 0; r < nsurv; r++) {
        cum += eg[r] / zall;
        if (r == 0 || cum <= 0.9f) rlast = r;
        else break;
      }
      float z2 = 0.f;
      for (int r = 0; r <= rlast; r++) z2 += eg[r];
      float best = -3.402823466e38f; int besti = V_CONST;
      for (int r = 0; r <= rlast; r++) {
        float sc = u2f(su[r]) + gg[r];
        int idx = sidx[r];
        if (sc > best || (sc == best && idx < besti)) { best = sc; besti = idx; }
      }
      out[b] = (float)besti;
      s_rlast = rlast; s_z2 = z2;
    }
    __syncthreads();
    const int rlast = s_rlast;
    const float z2 = s_z2;
    for (int r = tid; r <= rlast; r += NTHREADS) {
      prow[sidx[r]] = eg[r] / z2;
    }
  }
}

extern "C" void kernel_launch(void* const* d_in, const int* in_sizes, int n_in,
                              void* d_out, int out_size, void* d_ws, size_t ws_size,
                              hipStream_t stream) {
  const float* logits = (const float*)d_in[0];
  const int* generated = (const int*)d_in[1];
  float* out = (float*)d_out;
  const int B = in_sizes[0] / V_CONST;
  const int T = in_sizes[1] / B;
  hipLaunchKernelGGL(sample_kernel, dim3(B), dim3(NTHREADS), 0, stream,
                     logits, generated, out, B, T);
}